// Round 16
// baseline (154.212 us; speedup 1.0000x reference)
//
#include <hip/hip_runtime.h>
#include <math.h>

// ---------------------------------------------------------------------------
// AttentionBlock: GN(4,256) -> QKV 1x1 conv -> 2-head attn (N=1024, hd=128)
// -> proj -> +residual.  B=16, C=256, H=W=32 (N=1024), fp32 in/out.
// R19: prep + quarter-split qkv = R18 verbatim (152.2us best). attn_proj3p:
// T4 counted-vmcnt pipeline — triple-buffered K/V (3x32KB=96KB dynamic LDS,
// grid 256 -> still 1 block/CU), depth-2 prefetch, raw s_barrier + per-wave
// vmcnt(4) (never 0 in loop). Per iter: vmcnt(4) [own tile-jt loads done] ->
// s_barrier [all waves' jt loads done; jt-1 reads done] -> sched_barrier(0)
// [pin ds_reads + issue below barrier] -> issue jt+2 into freed buf -> compute.
// R18 counters: attn 60% stall from __syncthreads vmcnt(0) drain each tile.
// ---------------------------------------------------------------------------

typedef __attribute__((ext_vector_type(8))) short bf16x8;   // 8 bf16 = 4 VGPRs
typedef __attribute__((ext_vector_type(4))) float f32x4;

__device__ __forceinline__ unsigned short f2bf(float f) {   // RNE-ish
    union { float f; unsigned u; } v; v.f = f;
    return (unsigned short)((v.u + 0x7FFFu + ((v.u >> 16) & 1u)) >> 16);
}
__device__ __forceinline__ unsigned bfbits(float f) {       // +half (round up)
    union { float f; unsigned u; } v; v.f = f;
    return v.u + 0x8000u;
}
// pack two floats -> (bf(a) | bf(b)<<16) in 3 VALU ops
__device__ __forceinline__ unsigned packbf(float a, float b) {
    return __builtin_amdgcn_perm(bfbits(b), bfbits(a), 0x07060302u);
}

__device__ __forceinline__ void gload_lds16(const void* g, void* l) {
    __builtin_amdgcn_global_load_lds(
        (const __attribute__((address_space(1))) unsigned int*)g,
        (__attribute__((address_space(3))) unsigned int*)l, 16, 0, 0);
}

// ------------------------------------------- prep: weights->bf16 + GN stats
__global__ __launch_bounds__(256) void prep(const float* __restrict__ wq,
                                            const float* __restrict__ wk,
                                            const float* __restrict__ wv,
                                            const float* __restrict__ wp,
                                            unsigned short* __restrict__ oq,
                                            unsigned short* __restrict__ ok,
                                            unsigned short* __restrict__ ov,
                                            unsigned short* __restrict__ op,
                                            const float* __restrict__ x,
                                            float* __restrict__ acc) {
    int bid = blockIdx.x;
    if (bid < 256) {
        int idx = bid * 1024 + threadIdx.x * 4;
        int which = idx >> 16, i = idx & 65535;
        const float* src = (which == 0) ? wq : (which == 1) ? wk : (which == 2) ? wv : wp;
        unsigned short* dst = (which == 0) ? oq : (which == 1) ? ok : (which == 2) ? ov : op;
        // fold softmax scale 512^-0.5 AND log2(e) into wq (softmax uses exp2)
        float scl = (which == 0) ? (0.044194173824159216f * 1.4426950408889634f) : 1.0f;
        float4 v = *(const float4*)(src + i);
        ushort4 o;
        o.x = f2bf(v.x * scl); o.y = f2bf(v.y * scl);
        o.z = f2bf(v.z * scl); o.w = f2bf(v.w * scl);
        *(ushort4*)(dst + i) = o;
    } else {
        int bid2 = bid - 256;                  // [0,512)
        int bg = bid2 >> 3, ch = bid2 & 7;
        const float4* xp = (const float4*)(x + (size_t)bg * 65536 + ch * 8192);
        float s = 0.f, s2 = 0.f;
#pragma unroll
        for (int i = 0; i < 8; i++) {
            float4 v = xp[threadIdx.x + i * 256];
            s  += v.x + v.y + v.z + v.w;
            s2 += v.x * v.x + v.y * v.y + v.z * v.z + v.w * v.w;
        }
        for (int m = 1; m < 64; m <<= 1) { s += __shfl_xor(s, m); s2 += __shfl_xor(s2, m); }
        __shared__ float ls[8];
        int w = threadIdx.x >> 6, lane = threadIdx.x & 63;
        if (lane == 0) { ls[w] = s; ls[4 + w] = s2; }
        __syncthreads();
        if (threadIdx.x == 0) {
            acc[bg * 16 + ch * 2]     = ls[0] + ls[1] + ls[2] + ls[3];
            acc[bg * 16 + ch * 2 + 1] = ls[4] + ls[5] + ls[6] + ls[7];
        }
    }
}

// ---------- QKV GEMM fused with GN: quarter-split (64 out-ch x 64 n/block)
__global__ __launch_bounds__(256) void qkv_fused(const float* __restrict__ x,
                                                 const float* __restrict__ acc,
                                                 const float* __restrict__ gnw,
                                                 const float* __restrict__ gnb,
                                                 const unsigned short* __restrict__ wqb,
                                                 const unsigned short* __restrict__ wkb,
                                                 const unsigned short* __restrict__ wvb,
                                                 unsigned short* __restrict__ qt,
                                                 unsigned short* __restrict__ kt,
                                                 unsigned short* __restrict__ vv) {
    int b = blockIdx.z, quar = blockIdx.y, nx = blockIdx.x;
    int n0 = nx * 64;
    int half = quar >> 1, chb = (quar & 1) * 64;
    int t = threadIdx.x, w = t >> 6, lane = t & 63, quad = lane >> 4, c4 = lane & 15;
    __shared__ __align__(16) unsigned short xl[16896];   // 33 KB
    __shared__ float gs[8];
    if (t < 4) {
        float s0 = 0.f, s1 = 0.f;
#pragma unroll
        for (int p = 0; p < 8; p++) {
            s0 += acc[(b * 4 + t) * 16 + p * 2];
            s1 += acc[(b * 4 + t) * 16 + p * 2 + 1];
        }
        float mean = s0 * (1.f / 65536.f);
        float var = s1 * (1.f / 65536.f) - mean * mean;
        gs[2 * t] = mean;
        gs[2 * t + 1] = rsqrtf(var + 1e-5f);
    }
    __syncthreads();
    // ---- load + normalize x-tile -> xl [n 64][c pitch 264]
    {
        int col = t & 15, crow = t >> 4;
#pragma unroll
        for (int p = 0; p < 16; p++) {
            int c = p * 16 + crow;
            int g = c >> 6;
            float sc = gs[g * 2 + 1] * gnw[c];
            float bs = gnb[c] - gs[g * 2] * sc;
            float4 v = *(const float4*)(x + ((size_t)b * 256 + c) * 1024 + n0 + col * 4);
            int nl = col * 4;
            xl[(nl + 0) * 264 + c] = (unsigned short)(bfbits(fmaf(v.x, sc, bs)) >> 16);
            xl[(nl + 1) * 264 + c] = (unsigned short)(bfbits(fmaf(v.y, sc, bs)) >> 16);
            xl[(nl + 2) * 264 + c] = (unsigned short)(bfbits(fmaf(v.z, sc, bs)) >> 16);
            xl[(nl + 3) * 264 + c] = (unsigned short)(bfbits(fmaf(v.w, sc, bs)) >> 16);
        }
    }
    __syncthreads();
    int wm = (w >> 1) * 32, wn = (w & 1) * 32;
    int obase = quar * 64 + wm;            // absolute output channel base
    int bh = b * 2 + half;
    f32x4 aq[2][2] = {}, akk[2][2] = {}, av[2][2] = {};
#pragma unroll
    for (int k = 0; k < 256; k += 32) {
        bf16x8 bfr[2];
#pragma unroll
        for (int i = 0; i < 2; i++)
            bfr[i] = *(const bf16x8*)&xl[(wn + i * 16 + c4) * 264 + k + quad * 8];
#pragma unroll
        for (int mi = 0; mi < 2; mi++) {
            bf16x8 afq = *(const bf16x8*)(wqb + (size_t)(obase + mi * 16 + c4) * 256 + k + quad * 8);
            bf16x8 afk = *(const bf16x8*)(wkb + (size_t)(obase + mi * 16 + c4) * 256 + k + quad * 8);
            bf16x8 afv = *(const bf16x8*)(wvb + (size_t)(obase + mi * 16 + c4) * 256 + k + quad * 8);
#pragma unroll
            for (int ni = 0; ni < 2; ni++) {
                aq[mi][ni]  = __builtin_amdgcn_mfma_f32_16x16x32_bf16(afq, bfr[ni], aq[mi][ni], 0, 0, 0);
                akk[mi][ni] = __builtin_amdgcn_mfma_f32_16x16x32_bf16(afk, bfr[ni], akk[mi][ni], 0, 0, 0);
                av[mi][ni]  = __builtin_amdgcn_mfma_f32_16x16x32_bf16(afv, bfr[ni], av[mi][ni], 0, 0, 0);
            }
        }
    }
    __syncthreads();   // xl reads done; phase 2: Q-et@0 + K-et@4608, [64][72]
#pragma unroll
    for (int mi = 0; mi < 2; mi++)
#pragma unroll
        for (int ni = 0; ni < 2; ni++) {
            int row = wn + ni * 16 + c4;          // n-local [0,64)
            int col = wm + mi * 16 + quad * 4;    // ch-local [0,64)
            uint2 uq, uk;
            uq.x = packbf(aq[mi][ni][0], aq[mi][ni][1]);
            uq.y = packbf(aq[mi][ni][2], aq[mi][ni][3]);
            uk.x = packbf(akk[mi][ni][0], akk[mi][ni][1]);
            uk.y = packbf(akk[mi][ni][2], akk[mi][ni][3]);
            *(uint2*)&xl[row * 72 + col] = uq;
            *(uint2*)&xl[4608 + row * 72 + col] = uk;
        }
    __syncthreads();
#pragma unroll
    for (int p = 0; p < 2; p++) {
        int i = p * 32 + (t >> 3), off = (t & 7) * 8;   // i<64, off<64
        *(bf16x8*)(qt + ((size_t)bh * 1024 + n0 + i) * 128 + chb + off) =
            *(const bf16x8*)&xl[i * 72 + off];
        *(bf16x8*)(kt + ((size_t)bh * 1024 + n0 + i) * 128 + chb + off) =
            *(const bf16x8*)&xl[4608 + i * 72 + off];
    }
    __syncthreads();   // qt/kt reads done; phase 3: V-et [64 ch][72] @0
#pragma unroll
    for (int mi = 0; mi < 2; mi++)
#pragma unroll
        for (int ni = 0; ni < 2; ni++) {
            int row = wn + ni * 16 + c4;          // n-local
            int col = wm + mi * 16 + quad * 4;    // ch-local
#pragma unroll
            for (int r = 0; r < 4; r++)
                xl[(col + r) * 72 + row] = f2bf(av[mi][ni][r]);
        }
    __syncthreads();
#pragma unroll
    for (int p = 0; p < 2; p++) {
        int ch = p * 32 + (t >> 3), off = (t & 7) * 8;  // ch<64, off<64 (n)
        *(bf16x8*)(vv + ((size_t)bh * 128 + chb + ch) * 1024 + n0 + off) =
            *(const bf16x8*)&xl[ch * 72 + off];
    }
}

// ---- fused attention (both heads, KVBLK=32) + proj, T4 counted-vmcnt pipe
// grid 256, 512 thr = 8 waves (h=w>>2, wl=w&3). DYNAMIC LDS 96KB: 3 bufs x
// 32KB. Per buf: K @ buf*16384 + h*4096 + kc*512; V @ +8192. Depth-2
// prefetch; vmcnt(4) + raw s_barrier + sched_barrier(0) per tile (see R19
// header for the safety argument). Epilogue phases use __syncthreads.
__global__ __launch_bounds__(512) void attn_proj3p(const unsigned short* __restrict__ qt,
                                                   const unsigned short* __restrict__ kt,
                                                   const unsigned short* __restrict__ vv,
                                                   const unsigned short* __restrict__ wpb,
                                                   const float* __restrict__ x,
                                                   float* __restrict__ out) {
    extern __shared__ __align__(16) unsigned short smem[];   // 49152 shorts
    int L = blockIdx.x;
    int xcd = L & 7, jj = L >> 3;          // jj in [0,32)
    int b = ((jj >> 4) << 3) | xcd;        // batches {xcd, xcd+8} per XCD
    int qb = jj & 15;
    int tid = threadIdx.x, w = tid >> 6, lane = tid & 63;
    int quad = lane >> 4, c4 = lane & 15;
    int h = w >> 2, wl = w & 3;            // head, wave-in-head
    int bh = b * 2 + h;

    const unsigned short* qp = qt + (size_t)bh * 131072;
    int i0 = qb * 64 + wl * 16;

    bf16x8 bq[4];
#pragma unroll
    for (int kk = 0; kk < 4; kk++)
        bq[kk] = *(const bf16x8*)(qp + (size_t)(i0 + c4) * 128 + kk * 32 + quad * 8);

    float lsum = 0.f;
    f32x4 oacc[8] = {};

    // ---- stage one 32-row j-tile (both heads) into buf: 4 chunks per wave
    auto stage = [&](int j0, int buf) {
#pragma unroll
        for (int t = 0; t < 4; t++) {
            int cc = w * 4 + t;
            if (cc < 16) {
                int h2 = cc >> 3, kc = cc & 7;
                int np = kc >> 2, kk = kc & 3;
                const unsigned short* kp2 = kt + (size_t)(b * 2 + h2) * 131072;
                gload_lds16(kp2 + (size_t)(j0 + np * 16 + c4) * 128 + kk * 32 + quad * 8,
                            &smem[buf * 16384 + h2 * 4096 + kc * 512]);
            } else {
                int cc2 = cc - 16, h2 = cc2 >> 3, n = cc2 & 7;
                const unsigned short* vp2 = vv + (size_t)(b * 2 + h2) * 131072;
                gload_lds16(vp2 + (size_t)(n * 16 + c4) * 1024 + j0 + quad * 8,
                            &smem[buf * 16384 + 8192 + h2 * 4096 + n * 512]);
            }
        }
    };

    // prologue: tiles 0 and 1 in flight (8 loads/wave outstanding)
    stage(0, 0);
    stage(32, 1);

    for (int jt = 0; jt < 32; jt++) {
        int cur = jt % 3;
        // own tile-jt loads complete (4 newest = tile jt+1 may stay in flight)
        if (jt < 31) asm volatile("s_waitcnt vmcnt(4)" ::: "memory");
        else         asm volatile("s_waitcnt vmcnt(0)" ::: "memory");
        __builtin_amdgcn_s_barrier();          // all waves: jt done; jt-1 reads done
        __builtin_amdgcn_sched_barrier(0);     // pin ds_reads + issue below barrier
        if (jt < 30) stage((jt + 2) * 32, (jt + 2) % 3);   // buf freed by barrier

        f32x4 st[2] = {};
#pragma unroll
        for (int np = 0; np < 2; np++)
#pragma unroll
            for (int kk = 0; kk < 4; kk++) {
                bf16x8 ak = *(const bf16x8*)&smem[cur * 16384 + h * 4096 + (np * 4 + kk) * 512 + lane * 8];
                st[np] = __builtin_amdgcn_mfma_f32_16x16x32_bf16(ak, bq[kk], st[np], 0, 0, 0);
            }

#pragma unroll
        for (int np = 0; np < 2; np++)
#pragma unroll
            for (int r = 0; r < 4; r++) {
                float p = exp2f(st[np][r]);
                st[np][r] = p;
                lsum += p;
            }

        unsigned pk2[4];
#pragma unroll
        for (int r = 0; r < 4; r++)
            pk2[r] = packbf(st[0][r], st[1][r]);

        int sbase = ((lane & 16) ? 32 : 0) + c4;
        bool hi = (lane & 32) != 0;
        bf16x8 pa;
#pragma unroll
        for (int t = 0; t < 4; t++) {
            unsigned u  = (unsigned)__shfl((int)pk2[t], sbase);
            unsigned u2 = (unsigned)__shfl((int)pk2[t], sbase + 16);
            pa[t]     = (short)(hi ? (u >> 16)  : (u & 0xffffu));
            pa[4 + t] = (short)(hi ? (u2 >> 16) : (u2 & 0xffffu));
        }
#pragma unroll
        for (int n = 0; n < 8; n++) {
            bf16x8 bv = *(const bf16x8*)&smem[cur * 16384 + 8192 + h * 4096 + n * 512 + lane * 8];
            oacc[n] = __builtin_amdgcn_mfma_f32_16x16x32_bf16(pa, bv, oacc[n], 0, 0, 0);
        }
    }

    lsum += __shfl_xor(lsum, 16);
    lsum += __shfl_xor(lsum, 32);
    float inv = 1.0f / lsum;
    float ir[4];
#pragma unroll
    for (int r = 0; r < 4; r++) ir[r] = __shfl(inv, quad * 4 + r);

    __syncthreads();   // all K/V LDS reads done -> reuse smem as O-tile
#pragma unroll
    for (int n = 0; n < 8; n++)
#pragma unroll
        for (int r = 0; r < 4; r++) {
            int il = wl * 16 + quad * 4 + r;
            int c = h * 128 + n * 16 + c4;
            smem[il * 264 + c] = f2bf(oacc[n][r] * ir[r]);
        }
    __syncthreads();

    // ---- proj + residual: wave w owns output channels [w*32, w*32+32)
    int mbase = w * 32;
    f32x4 pacc[2][4] = {};
#pragma unroll
    for (int k = 0; k < 256; k += 32) {
        bf16x8 af[2], bfr[4];
#pragma unroll
        for (int mi = 0; mi < 2; mi++)
            af[mi] = *(const bf16x8*)(wpb + (size_t)(mbase + mi * 16 + c4) * 256 + k + quad * 8);
#pragma unroll
        for (int ni = 0; ni < 4; ni++)
            bfr[ni] = *(const bf16x8*)&smem[(ni * 16 + c4) * 264 + k + quad * 8];
#pragma unroll
        for (int mi = 0; mi < 2; mi++)
#pragma unroll
            for (int ni = 0; ni < 4; ni++)
                pacc[mi][ni] = __builtin_amdgcn_mfma_f32_16x16x32_bf16(
                    af[mi], bfr[ni], pacc[mi][ni], 0, 0, 0);
    }
#pragma unroll
    for (int mi = 0; mi < 2; mi++)
#pragma unroll
        for (int ni = 0; ni < 4; ni++)
#pragma unroll
            for (int r = 0; r < 4; r++) {
                int o = mbase + mi * 16 + quad * 4 + r;
                int i = qb * 64 + ni * 16 + c4;
                size_t idx = ((size_t)b * 256 + o) * 1024 + i;
                out[idx] = pacc[mi][ni][r] + x[idx];
            }
}

// ---------------------------------------------------------------------------
extern "C" void kernel_launch(void* const* d_in, const int* in_sizes, int n_in,
                              void* d_out, int out_size, void* d_ws, size_t ws_size,
                              hipStream_t stream) {
    const float* x   = (const float*)d_in[0];
    const float* gnw = (const float*)d_in[1];
    const float* gnb = (const float*)d_in[2];
    const float* wq  = (const float*)d_in[3];
    const float* wk  = (const float*)d_in[4];
    const float* wv  = (const float*)d_in[5];
    const float* wp  = (const float*)d_in[6];
    float* out = (float*)d_out;

    char* ws = (char*)d_ws;
    float* acc = (float*)ws;                                        //   4 KiB
    unsigned short* wqb = (unsigned short*)(ws + 4096);             // 128 KiB each
    unsigned short* wkb = (unsigned short*)(ws + 4096 + 131072);
    unsigned short* wvb = (unsigned short*)(ws + 4096 + 2 * 131072);
    unsigned short* wpb = (unsigned short*)(ws + 4096 + 3 * 131072);
    size_t base = 4096 + 4 * 131072;
    const size_t SZ = (size_t)16 * 1024 * 256 * 2;  // 8 MiB each
    unsigned short* qt = (unsigned short*)(ws + base);
    unsigned short* kt = (unsigned short*)(ws + base + SZ);
    unsigned short* vv = (unsigned short*)(ws + base + 2 * SZ);

    prep<<<768, 256, 0, stream>>>(wq, wk, wv, wp, wqb, wkb, wvb, wpb, x, acc);
    qkv_fused<<<dim3(16, 4, 16), 256, 0, stream>>>(x, acc, gnw, gnb,
                                                   wqb, wkb, wvb, qt, kt, vv);
    attn_proj3p<<<256, 512, 98304, stream>>>(qt, kt, vv, wpb, x, out);
}

// Round 17
// 152.091 us; speedup vs baseline: 1.0139x; 1.0139x over previous
//
#include <hip/hip_runtime.h>
#include <math.h>

// ---------------------------------------------------------------------------
// AttentionBlock: GN(4,256) -> QKV 1x1 conv -> 2-head attn (N=1024, hd=128)
// -> proj -> +residual.  B=16, C=256, H=W=32 (N=1024), fp32 in/out.
// R20 = R18 exact (152.2us session best). Structure: prep (wconv+stats) ->
// quarter-split qkv (1024 blocks, 33KB LDS, 4/CU) -> fused attn+proj
// (256 blocks x 512thr, both heads, KVBLK=32, 64KB LDS, O-tile in LDS,
// proj+residual in-block; no ot round-trip).
// Session ledger: R12 attn+proj fusion -10us; R18 qkv ch-split -7us.
// Nulls/losses: coop grid.sync (R7/8), V-direct (R9), atomics (R10),
// KVBLK 64 (R14), occupancy pins (R13/16/17), inline w-cvt (R15),
// counted-vmcnt pipe (R19 neutral). Fixed floor: 43us harness fill.
// ---------------------------------------------------------------------------

typedef __attribute__((ext_vector_type(8))) short bf16x8;   // 8 bf16 = 4 VGPRs
typedef __attribute__((ext_vector_type(4))) float f32x4;

__device__ __forceinline__ unsigned short f2bf(float f) {   // RNE-ish
    union { float f; unsigned u; } v; v.f = f;
    return (unsigned short)((v.u + 0x7FFFu + ((v.u >> 16) & 1u)) >> 16);
}
__device__ __forceinline__ unsigned bfbits(float f) {       // +half (round up)
    union { float f; unsigned u; } v; v.f = f;
    return v.u + 0x8000u;
}
// pack two floats -> (bf(a) | bf(b)<<16) in 3 VALU ops
__device__ __forceinline__ unsigned packbf(float a, float b) {
    return __builtin_amdgcn_perm(bfbits(b), bfbits(a), 0x07060302u);
}

__device__ __forceinline__ void gload_lds16(const void* g, void* l) {
    __builtin_amdgcn_global_load_lds(
        (const __attribute__((address_space(1))) unsigned int*)g,
        (__attribute__((address_space(3))) unsigned int*)l, 16, 0, 0);
}

// ------------------------------------------- prep: weights->bf16 + GN stats
__global__ __launch_bounds__(256) void prep(const float* __restrict__ wq,
                                            const float* __restrict__ wk,
                                            const float* __restrict__ wv,
                                            const float* __restrict__ wp,
                                            unsigned short* __restrict__ oq,
                                            unsigned short* __restrict__ ok,
                                            unsigned short* __restrict__ ov,
                                            unsigned short* __restrict__ op,
                                            const float* __restrict__ x,
                                            float* __restrict__ acc) {
    int bid = blockIdx.x;
    if (bid < 256) {
        int idx = bid * 1024 + threadIdx.x * 4;
        int which = idx >> 16, i = idx & 65535;
        const float* src = (which == 0) ? wq : (which == 1) ? wk : (which == 2) ? wv : wp;
        unsigned short* dst = (which == 0) ? oq : (which == 1) ? ok : (which == 2) ? ov : op;
        // fold softmax scale 512^-0.5 AND log2(e) into wq (softmax uses exp2)
        float scl = (which == 0) ? (0.044194173824159216f * 1.4426950408889634f) : 1.0f;
        float4 v = *(const float4*)(src + i);
        ushort4 o;
        o.x = f2bf(v.x * scl); o.y = f2bf(v.y * scl);
        o.z = f2bf(v.z * scl); o.w = f2bf(v.w * scl);
        *(ushort4*)(dst + i) = o;
    } else {
        int bid2 = bid - 256;                  // [0,512)
        int bg = bid2 >> 3, ch = bid2 & 7;
        const float4* xp = (const float4*)(x + (size_t)bg * 65536 + ch * 8192);
        float s = 0.f, s2 = 0.f;
#pragma unroll
        for (int i = 0; i < 8; i++) {
            float4 v = xp[threadIdx.x + i * 256];
            s  += v.x + v.y + v.z + v.w;
            s2 += v.x * v.x + v.y * v.y + v.z * v.z + v.w * v.w;
        }
        for (int m = 1; m < 64; m <<= 1) { s += __shfl_xor(s, m); s2 += __shfl_xor(s2, m); }
        __shared__ float ls[8];
        int w = threadIdx.x >> 6, lane = threadIdx.x & 63;
        if (lane == 0) { ls[w] = s; ls[4 + w] = s2; }
        __syncthreads();
        if (threadIdx.x == 0) {
            acc[bg * 16 + ch * 2]     = ls[0] + ls[1] + ls[2] + ls[3];
            acc[bg * 16 + ch * 2 + 1] = ls[4] + ls[5] + ls[6] + ls[7];
        }
    }
}

// ---------- QKV GEMM fused with GN: quarter-split (64 out-ch x 64 n/block)
// grid (16 nx, 4 quarter, 16 b) = 1024 blocks, 256 thr, LDS 33KB -> 4/CU.
__global__ __launch_bounds__(256) void qkv_fused(const float* __restrict__ x,
                                                 const float* __restrict__ acc,
                                                 const float* __restrict__ gnw,
                                                 const float* __restrict__ gnb,
                                                 const unsigned short* __restrict__ wqb,
                                                 const unsigned short* __restrict__ wkb,
                                                 const unsigned short* __restrict__ wvb,
                                                 unsigned short* __restrict__ qt,
                                                 unsigned short* __restrict__ kt,
                                                 unsigned short* __restrict__ vv) {
    int b = blockIdx.z, quar = blockIdx.y, nx = blockIdx.x;
    int n0 = nx * 64;
    int half = quar >> 1, chb = (quar & 1) * 64;
    int t = threadIdx.x, w = t >> 6, lane = t & 63, quad = lane >> 4, c4 = lane & 15;
    __shared__ __align__(16) unsigned short xl[16896];   // 33 KB
    __shared__ float gs[8];
    if (t < 4) {
        float s0 = 0.f, s1 = 0.f;
#pragma unroll
        for (int p = 0; p < 8; p++) {
            s0 += acc[(b * 4 + t) * 16 + p * 2];
            s1 += acc[(b * 4 + t) * 16 + p * 2 + 1];
        }
        float mean = s0 * (1.f / 65536.f);
        float var = s1 * (1.f / 65536.f) - mean * mean;
        gs[2 * t] = mean;
        gs[2 * t + 1] = rsqrtf(var + 1e-5f);
    }
    __syncthreads();
    // ---- load + normalize x-tile -> xl [n 64][c pitch 264]
    {
        int col = t & 15, crow = t >> 4;
#pragma unroll
        for (int p = 0; p < 16; p++) {
            int c = p * 16 + crow;
            int g = c >> 6;
            float sc = gs[g * 2 + 1] * gnw[c];
            float bs = gnb[c] - gs[g * 2] * sc;
            float4 v = *(const float4*)(x + ((size_t)b * 256 + c) * 1024 + n0 + col * 4);
            int nl = col * 4;
            xl[(nl + 0) * 264 + c] = (unsigned short)(bfbits(fmaf(v.x, sc, bs)) >> 16);
            xl[(nl + 1) * 264 + c] = (unsigned short)(bfbits(fmaf(v.y, sc, bs)) >> 16);
            xl[(nl + 2) * 264 + c] = (unsigned short)(bfbits(fmaf(v.z, sc, bs)) >> 16);
            xl[(nl + 3) * 264 + c] = (unsigned short)(bfbits(fmaf(v.w, sc, bs)) >> 16);
        }
    }
    __syncthreads();
    int wm = (w >> 1) * 32, wn = (w & 1) * 32;
    int obase = quar * 64 + wm;            // absolute output channel base
    int bh = b * 2 + half;
    f32x4 aq[2][2] = {}, akk[2][2] = {}, av[2][2] = {};
#pragma unroll
    for (int k = 0; k < 256; k += 32) {
        bf16x8 bfr[2];
#pragma unroll
        for (int i = 0; i < 2; i++)
            bfr[i] = *(const bf16x8*)&xl[(wn + i * 16 + c4) * 264 + k + quad * 8];
#pragma unroll
        for (int mi = 0; mi < 2; mi++) {
            bf16x8 afq = *(const bf16x8*)(wqb + (size_t)(obase + mi * 16 + c4) * 256 + k + quad * 8);
            bf16x8 afk = *(const bf16x8*)(wkb + (size_t)(obase + mi * 16 + c4) * 256 + k + quad * 8);
            bf16x8 afv = *(const bf16x8*)(wvb + (size_t)(obase + mi * 16 + c4) * 256 + k + quad * 8);
#pragma unroll
            for (int ni = 0; ni < 2; ni++) {
                aq[mi][ni]  = __builtin_amdgcn_mfma_f32_16x16x32_bf16(afq, bfr[ni], aq[mi][ni], 0, 0, 0);
                akk[mi][ni] = __builtin_amdgcn_mfma_f32_16x16x32_bf16(afk, bfr[ni], akk[mi][ni], 0, 0, 0);
                av[mi][ni]  = __builtin_amdgcn_mfma_f32_16x16x32_bf16(afv, bfr[ni], av[mi][ni], 0, 0, 0);
            }
        }
    }
    __syncthreads();   // xl reads done; phase 2: Q-et@0 + K-et@4608, [64][72]
#pragma unroll
    for (int mi = 0; mi < 2; mi++)
#pragma unroll
        for (int ni = 0; ni < 2; ni++) {
            int row = wn + ni * 16 + c4;          // n-local [0,64)
            int col = wm + mi * 16 + quad * 4;    // ch-local [0,64)
            uint2 uq, uk;
            uq.x = packbf(aq[mi][ni][0], aq[mi][ni][1]);
            uq.y = packbf(aq[mi][ni][2], aq[mi][ni][3]);
            uk.x = packbf(akk[mi][ni][0], akk[mi][ni][1]);
            uk.y = packbf(akk[mi][ni][2], akk[mi][ni][3]);
            *(uint2*)&xl[row * 72 + col] = uq;
            *(uint2*)&xl[4608 + row * 72 + col] = uk;
        }
    __syncthreads();
#pragma unroll
    for (int p = 0; p < 2; p++) {
        int i = p * 32 + (t >> 3), off = (t & 7) * 8;   // i<64, off<64
        *(bf16x8*)(qt + ((size_t)bh * 1024 + n0 + i) * 128 + chb + off) =
            *(const bf16x8*)&xl[i * 72 + off];
        *(bf16x8*)(kt + ((size_t)bh * 1024 + n0 + i) * 128 + chb + off) =
            *(const bf16x8*)&xl[4608 + i * 72 + off];
    }
    __syncthreads();   // qt/kt reads done; phase 3: V-et [64 ch][72] @0
#pragma unroll
    for (int mi = 0; mi < 2; mi++)
#pragma unroll
        for (int ni = 0; ni < 2; ni++) {
            int row = wn + ni * 16 + c4;          // n-local
            int col = wm + mi * 16 + quad * 4;    // ch-local
#pragma unroll
            for (int r = 0; r < 4; r++)
                xl[(col + r) * 72 + row] = f2bf(av[mi][ni][r]);
        }
    __syncthreads();
#pragma unroll
    for (int p = 0; p < 2; p++) {
        int ch = p * 32 + (t >> 3), off = (t & 7) * 8;  // ch<64, off<64 (n)
        *(bf16x8*)(vv + ((size_t)bh * 128 + chb + ch) * 1024 + n0 + off) =
            *(const bf16x8*)&xl[ch * 72 + off];
    }
}

// ------- fused attention (both heads, KVBLK=32) + proj + residual (R12 best)
__global__ __launch_bounds__(512) void attn_proj3(const unsigned short* __restrict__ qt,
                                                  const unsigned short* __restrict__ kt,
                                                  const unsigned short* __restrict__ vv,
                                                  const unsigned short* __restrict__ wpb,
                                                  const float* __restrict__ x,
                                                  float* __restrict__ out) {
    int L = blockIdx.x;
    int xcd = L & 7, jj = L >> 3;          // jj in [0,32)
    int b = ((jj >> 4) << 3) | xcd;        // batches {xcd, xcd+8} per XCD
    int qb = jj & 15;
    int tid = threadIdx.x, w = tid >> 6, lane = tid & 63;
    int quad = lane >> 4, c4 = lane & 15;
    int h = w >> 2, wl = w & 3;            // head, wave-in-head
    int bh = b * 2 + h;
    __shared__ __align__(16) unsigned short smem[32768];   // 64 KiB exactly

    const unsigned short* qp = qt + (size_t)bh * 131072;
    int i0 = qb * 64 + wl * 16;

    bf16x8 bq[4];
#pragma unroll
    for (int kk = 0; kk < 4; kk++)
        bq[kk] = *(const bf16x8*)(qp + (size_t)(i0 + c4) * 128 + kk * 32 + quad * 8);

    float lsum = 0.f;
    f32x4 oacc[8] = {};

#pragma unroll
    for (int t = 0; t < 4; t++) {
        int cc = w * 4 + t;
        if (cc < 16) {
            int h2 = cc >> 3, kc = cc & 7;
            int np = kc >> 2, kk = kc & 3;
            const unsigned short* kp2 = kt + (size_t)(b * 2 + h2) * 131072;
            gload_lds16(kp2 + (size_t)(np * 16 + c4) * 128 + kk * 32 + quad * 8,
                        &smem[h2 * 4096 + kc * 512]);
        } else {
            int cc2 = cc - 16, h2 = cc2 >> 3, n = cc2 & 7;
            const unsigned short* vp2 = vv + (size_t)(b * 2 + h2) * 131072;
            gload_lds16(vp2 + (size_t)(n * 16 + c4) * 1024 + quad * 8,
                        &smem[16384 + h2 * 4096 + n * 512]);
        }
    }

    for (int jt = 0; jt < 32; jt++) {
        int cur = jt & 1;
        __syncthreads();
        if (jt < 31) {
            int j0n = (jt + 1) * 32, nb = cur ^ 1;
#pragma unroll
            for (int t = 0; t < 4; t++) {
                int cc = w * 4 + t;
                if (cc < 16) {
                    int h2 = cc >> 3, kc = cc & 7;
                    int np = kc >> 2, kk = kc & 3;
                    const unsigned short* kp2 = kt + (size_t)(b * 2 + h2) * 131072;
                    gload_lds16(kp2 + (size_t)(j0n + np * 16 + c4) * 128 + kk * 32 + quad * 8,
                                &smem[nb * 8192 + h2 * 4096 + kc * 512]);
                } else {
                    int cc2 = cc - 16, h2 = cc2 >> 3, n = cc2 & 7;
                    const unsigned short* vp2 = vv + (size_t)(b * 2 + h2) * 131072;
                    gload_lds16(vp2 + (size_t)(n * 16 + c4) * 1024 + j0n + quad * 8,
                                &smem[16384 + nb * 8192 + h2 * 4096 + n * 512]);
                }
            }
        }

        f32x4 st[2] = {};
#pragma unroll
        for (int np = 0; np < 2; np++)
#pragma unroll
            for (int kk = 0; kk < 4; kk++) {
                bf16x8 ak = *(const bf16x8*)&smem[cur * 8192 + h * 4096 + (np * 4 + kk) * 512 + lane * 8];
                st[np] = __builtin_amdgcn_mfma_f32_16x16x32_bf16(ak, bq[kk], st[np], 0, 0, 0);
            }

#pragma unroll
        for (int np = 0; np < 2; np++)
#pragma unroll
            for (int r = 0; r < 4; r++) {
                float p = exp2f(st[np][r]);
                st[np][r] = p;
                lsum += p;
            }

        unsigned pk2[4];
#pragma unroll
        for (int r = 0; r < 4; r++)
            pk2[r] = packbf(st[0][r], st[1][r]);

        int sbase = ((lane & 16) ? 32 : 0) + c4;
        bool hi = (lane & 32) != 0;
        bf16x8 pa;
#pragma unroll
        for (int t = 0; t < 4; t++) {
            unsigned u  = (unsigned)__shfl((int)pk2[t], sbase);
            unsigned u2 = (unsigned)__shfl((int)pk2[t], sbase + 16);
            pa[t]     = (short)(hi ? (u >> 16)  : (u & 0xffffu));
            pa[4 + t] = (short)(hi ? (u2 >> 16) : (u2 & 0xffffu));
        }
#pragma unroll
        for (int n = 0; n < 8; n++) {
            bf16x8 bv = *(const bf16x8*)&smem[16384 + cur * 8192 + h * 4096 + n * 512 + lane * 8];
            oacc[n] = __builtin_amdgcn_mfma_f32_16x16x32_bf16(pa, bv, oacc[n], 0, 0, 0);
        }
    }

    lsum += __shfl_xor(lsum, 16);
    lsum += __shfl_xor(lsum, 32);
    float inv = 1.0f / lsum;
    float ir[4];
#pragma unroll
    for (int r = 0; r < 4; r++) ir[r] = __shfl(inv, quad * 4 + r);

    __syncthreads();   // all K/V LDS reads done -> reuse smem as O-tile
#pragma unroll
    for (int n = 0; n < 8; n++)
#pragma unroll
        for (int r = 0; r < 4; r++) {
            int il = wl * 16 + quad * 4 + r;
            int c = h * 128 + n * 16 + c4;
            smem[il * 264 + c] = f2bf(oacc[n][r] * ir[r]);
        }
    __syncthreads();

    // ---- proj + residual: wave w owns output channels [w*32, w*32+32)
    int mbase = w * 32;
    f32x4 pacc[2][4] = {};
#pragma unroll
    for (int k = 0; k < 256; k += 32) {
        bf16x8 af[2], bfr[4];
#pragma unroll
        for (int mi = 0; mi < 2; mi++)
            af[mi] = *(const bf16x8*)(wpb + (size_t)(mbase + mi * 16 + c4) * 256 + k + quad * 8);
#pragma unroll
        for (int ni = 0; ni < 4; ni++)
            bfr[ni] = *(const bf16x8*)&smem[(ni * 16 + c4) * 264 + k + quad * 8];
#pragma unroll
        for (int mi = 0; mi < 2; mi++)
#pragma unroll
            for (int ni = 0; ni < 4; ni++)
                pacc[mi][ni] = __builtin_amdgcn_mfma_f32_16x16x32_bf16(
                    af[mi], bfr[ni], pacc[mi][ni], 0, 0, 0);
    }
#pragma unroll
    for (int mi = 0; mi < 2; mi++)
#pragma unroll
        for (int ni = 0; ni < 4; ni++)
#pragma unroll
            for (int r = 0; r < 4; r++) {
                int o = mbase + mi * 16 + quad * 4 + r;
                int i = qb * 64 + ni * 16 + c4;
                size_t idx = ((size_t)b * 256 + o) * 1024 + i;
                out[idx] = pacc[mi][ni][r] + x[idx];
            }
}

// ---------------------------------------------------------------------------
extern "C" void kernel_launch(void* const* d_in, const int* in_sizes, int n_in,
                              void* d_out, int out_size, void* d_ws, size_t ws_size,
                              hipStream_t stream) {
    const float* x   = (const float*)d_in[0];
    const float* gnw = (const float*)d_in[1];
    const float* gnb = (const float*)d_in[2];
    const float* wq  = (const float*)d_in[3];
    const float* wk  = (const float*)d_in[4];
    const float* wv  = (const float*)d_in[5];
    const float* wp  = (const float*)d_in[6];
    float* out = (float*)d_out;

    char* ws = (char*)d_ws;
    float* acc = (float*)ws;                                        //   4 KiB
    unsigned short* wqb = (unsigned short*)(ws + 4096);             // 128 KiB each
    unsigned short* wkb = (unsigned short*)(ws + 4096 + 131072);
    unsigned short* wvb = (unsigned short*)(ws + 4096 + 2 * 131072);
    unsigned short* wpb = (unsigned short*)(ws + 4096 + 3 * 131072);
    size_t base = 4096 + 4 * 131072;
    const size_t SZ = (size_t)16 * 1024 * 256 * 2;  // 8 MiB each
    unsigned short* qt = (unsigned short*)(ws + base);
    unsigned short* kt = (unsigned short*)(ws + base + SZ);
    unsigned short* vv = (unsigned short*)(ws + base + 2 * SZ);

    prep<<<768, 256, 0, stream>>>(wq, wk, wv, wp, wqb, wkb, wvb, wpb, x, acc);
    qkv_fused<<<dim3(16, 4, 16), 256, 0, stream>>>(x, acc, gnw, gnb,
                                                   wqb, wkb, wvb, qt, kt, vv);
    attn_proj3<<<256, 512, 0, stream>>>(qt, kt, vv, wpb, x, out);
}

// Round 18
// 151.601 us; speedup vs baseline: 1.0172x; 1.0032x over previous
//
#include <hip/hip_runtime.h>
#include <math.h>

// ---------------------------------------------------------------------------
// AttentionBlock: GN(4,256) -> QKV 1x1 conv -> 2-head attn (N=1024, hd=128)
// -> proj -> +residual.  B=16, C=256, H=W=32 (N=1024), fp32 in/out.
// R21 = R20 (152.1us, twice-verified) + ONE change: qkv x-tile XOR swizzle.
// The GN-normalize scatter store (xl[row*264+c], 16 cols -> 2 bank residues,
// ~16-way conflict, 2.2M cycles) now stores at c ^ ((row>>2)&7)<<3; the
// k-loop bf16x8 reads apply the same XOR (8-aligned + 8-granular swizzle =>
// chunks stay contiguous; round-trip exact). Post-barrier et-phases untouched.
// Ledger: R12 fusion -10us, R18 qkv split -7us; nulls: coop sync, V-direct,
// atomics, KVBLK64, occupancy pins, inline w-cvt, counted-vmcnt.
// ---------------------------------------------------------------------------

typedef __attribute__((ext_vector_type(8))) short bf16x8;   // 8 bf16 = 4 VGPRs
typedef __attribute__((ext_vector_type(4))) float f32x4;

__device__ __forceinline__ unsigned short f2bf(float f) {   // RNE-ish
    union { float f; unsigned u; } v; v.f = f;
    return (unsigned short)((v.u + 0x7FFFu + ((v.u >> 16) & 1u)) >> 16);
}
__device__ __forceinline__ unsigned bfbits(float f) {       // +half (round up)
    union { float f; unsigned u; } v; v.f = f;
    return v.u + 0x8000u;
}
// pack two floats -> (bf(a) | bf(b)<<16) in 3 VALU ops
__device__ __forceinline__ unsigned packbf(float a, float b) {
    return __builtin_amdgcn_perm(bfbits(b), bfbits(a), 0x07060302u);
}

__device__ __forceinline__ void gload_lds16(const void* g, void* l) {
    __builtin_amdgcn_global_load_lds(
        (const __attribute__((address_space(1))) unsigned int*)g,
        (__attribute__((address_space(3))) unsigned int*)l, 16, 0, 0);
}

// ------------------------------------------- prep: weights->bf16 + GN stats
__global__ __launch_bounds__(256) void prep(const float* __restrict__ wq,
                                            const float* __restrict__ wk,
                                            const float* __restrict__ wv,
                                            const float* __restrict__ wp,
                                            unsigned short* __restrict__ oq,
                                            unsigned short* __restrict__ ok,
                                            unsigned short* __restrict__ ov,
                                            unsigned short* __restrict__ op,
                                            const float* __restrict__ x,
                                            float* __restrict__ acc) {
    int bid = blockIdx.x;
    if (bid < 256) {
        int idx = bid * 1024 + threadIdx.x * 4;
        int which = idx >> 16, i = idx & 65535;
        const float* src = (which == 0) ? wq : (which == 1) ? wk : (which == 2) ? wv : wp;
        unsigned short* dst = (which == 0) ? oq : (which == 1) ? ok : (which == 2) ? ov : op;
        // fold softmax scale 512^-0.5 AND log2(e) into wq (softmax uses exp2)
        float scl = (which == 0) ? (0.044194173824159216f * 1.4426950408889634f) : 1.0f;
        float4 v = *(const float4*)(src + i);
        ushort4 o;
        o.x = f2bf(v.x * scl); o.y = f2bf(v.y * scl);
        o.z = f2bf(v.z * scl); o.w = f2bf(v.w * scl);
        *(ushort4*)(dst + i) = o;
    } else {
        int bid2 = bid - 256;                  // [0,512)
        int bg = bid2 >> 3, ch = bid2 & 7;
        const float4* xp = (const float4*)(x + (size_t)bg * 65536 + ch * 8192);
        float s = 0.f, s2 = 0.f;
#pragma unroll
        for (int i = 0; i < 8; i++) {
            float4 v = xp[threadIdx.x + i * 256];
            s  += v.x + v.y + v.z + v.w;
            s2 += v.x * v.x + v.y * v.y + v.z * v.z + v.w * v.w;
        }
        for (int m = 1; m < 64; m <<= 1) { s += __shfl_xor(s, m); s2 += __shfl_xor(s2, m); }
        __shared__ float ls[8];
        int w = threadIdx.x >> 6, lane = threadIdx.x & 63;
        if (lane == 0) { ls[w] = s; ls[4 + w] = s2; }
        __syncthreads();
        if (threadIdx.x == 0) {
            acc[bg * 16 + ch * 2]     = ls[0] + ls[1] + ls[2] + ls[3];
            acc[bg * 16 + ch * 2 + 1] = ls[4] + ls[5] + ls[6] + ls[7];
        }
    }
}

// ---------- QKV GEMM fused with GN: quarter-split (64 out-ch x 64 n/block)
// grid (16 nx, 4 quarter, 16 b) = 1024 blocks, 256 thr, LDS 33KB -> 4/CU.
// x-tile stores/reads XOR-swizzled: idx = row*264 + (coff ^ ((row>>2)&7)<<3).
__global__ __launch_bounds__(256) void qkv_fused(const float* __restrict__ x,
                                                 const float* __restrict__ acc,
                                                 const float* __restrict__ gnw,
                                                 const float* __restrict__ gnb,
                                                 const unsigned short* __restrict__ wqb,
                                                 const unsigned short* __restrict__ wkb,
                                                 const unsigned short* __restrict__ wvb,
                                                 unsigned short* __restrict__ qt,
                                                 unsigned short* __restrict__ kt,
                                                 unsigned short* __restrict__ vv) {
    int b = blockIdx.z, quar = blockIdx.y, nx = blockIdx.x;
    int n0 = nx * 64;
    int half = quar >> 1, chb = (quar & 1) * 64;
    int t = threadIdx.x, w = t >> 6, lane = t & 63, quad = lane >> 4, c4 = lane & 15;
    __shared__ __align__(16) unsigned short xl[16896];   // 33 KB
    __shared__ float gs[8];
    if (t < 4) {
        float s0 = 0.f, s1 = 0.f;
#pragma unroll
        for (int p = 0; p < 8; p++) {
            s0 += acc[(b * 4 + t) * 16 + p * 2];
            s1 += acc[(b * 4 + t) * 16 + p * 2 + 1];
        }
        float mean = s0 * (1.f / 65536.f);
        float var = s1 * (1.f / 65536.f) - mean * mean;
        gs[2 * t] = mean;
        gs[2 * t + 1] = rsqrtf(var + 1e-5f);
    }
    __syncthreads();
    // ---- load + normalize x-tile -> xl [n 64][c pitch 264], swizzled store
    {
        int col = t & 15, crow = t >> 4;
        int sw = (col & 7) << 3;               // row>>2 == col for rows nl..nl+3
#pragma unroll
        for (int p = 0; p < 16; p++) {
            int c = p * 16 + crow;
            int g = c >> 6;
            float sc = gs[g * 2 + 1] * gnw[c];
            float bs = gnb[c] - gs[g * 2] * sc;
            float4 v = *(const float4*)(x + ((size_t)b * 256 + c) * 1024 + n0 + col * 4);
            int nl = col * 4;
            int cs = c ^ sw;
            xl[(nl + 0) * 264 + cs] = (unsigned short)(bfbits(fmaf(v.x, sc, bs)) >> 16);
            xl[(nl + 1) * 264 + cs] = (unsigned short)(bfbits(fmaf(v.y, sc, bs)) >> 16);
            xl[(nl + 2) * 264 + cs] = (unsigned short)(bfbits(fmaf(v.z, sc, bs)) >> 16);
            xl[(nl + 3) * 264 + cs] = (unsigned short)(bfbits(fmaf(v.w, sc, bs)) >> 16);
        }
    }
    __syncthreads();
    int wm = (w >> 1) * 32, wn = (w & 1) * 32;
    int obase = quar * 64 + wm;            // absolute output channel base
    int bh = b * 2 + half;
    f32x4 aq[2][2] = {}, akk[2][2] = {}, av[2][2] = {};
#pragma unroll
    for (int k = 0; k < 256; k += 32) {
        bf16x8 bfr[2];
#pragma unroll
        for (int i = 0; i < 2; i++) {
            int row = wn + i * 16 + c4;
            int sw = ((row >> 2) & 7) << 3;
            bfr[i] = *(const bf16x8*)&xl[row * 264 + ((k + quad * 8) ^ sw)];
        }
#pragma unroll
        for (int mi = 0; mi < 2; mi++) {
            bf16x8 afq = *(const bf16x8*)(wqb + (size_t)(obase + mi * 16 + c4) * 256 + k + quad * 8);
            bf16x8 afk = *(const bf16x8*)(wkb + (size_t)(obase + mi * 16 + c4) * 256 + k + quad * 8);
            bf16x8 afv = *(const bf16x8*)(wvb + (size_t)(obase + mi * 16 + c4) * 256 + k + quad * 8);
#pragma unroll
            for (int ni = 0; ni < 2; ni++) {
                aq[mi][ni]  = __builtin_amdgcn_mfma_f32_16x16x32_bf16(afq, bfr[ni], aq[mi][ni], 0, 0, 0);
                akk[mi][ni] = __builtin_amdgcn_mfma_f32_16x16x32_bf16(afk, bfr[ni], akk[mi][ni], 0, 0, 0);
                av[mi][ni]  = __builtin_amdgcn_mfma_f32_16x16x32_bf16(afv, bfr[ni], av[mi][ni], 0, 0, 0);
            }
        }
    }
    __syncthreads();   // xl reads done; phase 2: Q-et@0 + K-et@4608, [64][72]
#pragma unroll
    for (int mi = 0; mi < 2; mi++)
#pragma unroll
        for (int ni = 0; ni < 2; ni++) {
            int row = wn + ni * 16 + c4;          // n-local [0,64)
            int col = wm + mi * 16 + quad * 4;    // ch-local [0,64)
            uint2 uq, uk;
            uq.x = packbf(aq[mi][ni][0], aq[mi][ni][1]);
            uq.y = packbf(aq[mi][ni][2], aq[mi][ni][3]);
            uk.x = packbf(akk[mi][ni][0], akk[mi][ni][1]);
            uk.y = packbf(akk[mi][ni][2], akk[mi][ni][3]);
            *(uint2*)&xl[row * 72 + col] = uq;
            *(uint2*)&xl[4608 + row * 72 + col] = uk;
        }
    __syncthreads();
#pragma unroll
    for (int p = 0; p < 2; p++) {
        int i = p * 32 + (t >> 3), off = (t & 7) * 8;   // i<64, off<64
        *(bf16x8*)(qt + ((size_t)bh * 1024 + n0 + i) * 128 + chb + off) =
            *(const bf16x8*)&xl[i * 72 + off];
        *(bf16x8*)(kt + ((size_t)bh * 1024 + n0 + i) * 128 + chb + off) =
            *(const bf16x8*)&xl[4608 + i * 72 + off];
    }
    __syncthreads();   // qt/kt reads done; phase 3: V-et [64 ch][72] @0
#pragma unroll
    for (int mi = 0; mi < 2; mi++)
#pragma unroll
        for (int ni = 0; ni < 2; ni++) {
            int row = wn + ni * 16 + c4;          // n-local
            int col = wm + mi * 16 + quad * 4;    // ch-local
#pragma unroll
            for (int r = 0; r < 4; r++)
                xl[(col + r) * 72 + row] = f2bf(av[mi][ni][r]);
        }
    __syncthreads();
#pragma unroll
    for (int p = 0; p < 2; p++) {
        int ch = p * 32 + (t >> 3), off = (t & 7) * 8;  // ch<64, off<64 (n)
        *(bf16x8*)(vv + ((size_t)bh * 128 + chb + ch) * 1024 + n0 + off) =
            *(const bf16x8*)&xl[ch * 72 + off];
    }
}

// ------- fused attention (both heads, KVBLK=32) + proj + residual (R12 best)
__global__ __launch_bounds__(512) void attn_proj3(const unsigned short* __restrict__ qt,
                                                  const unsigned short* __restrict__ kt,
                                                  const unsigned short* __restrict__ vv,
                                                  const unsigned short* __restrict__ wpb,
                                                  const float* __restrict__ x,
                                                  float* __restrict__ out) {
    int L = blockIdx.x;
    int xcd = L & 7, jj = L >> 3;          // jj in [0,32)
    int b = ((jj >> 4) << 3) | xcd;        // batches {xcd, xcd+8} per XCD
    int qb = jj & 15;
    int tid = threadIdx.x, w = tid >> 6, lane = tid & 63;
    int quad = lane >> 4, c4 = lane & 15;
    int h = w >> 2, wl = w & 3;            // head, wave-in-head
    int bh = b * 2 + h;
    __shared__ __align__(16) unsigned short smem[32768];   // 64 KiB exactly

    const unsigned short* qp = qt + (size_t)bh * 131072;
    int i0 = qb * 64 + wl * 16;

    bf16x8 bq[4];
#pragma unroll
    for (int kk = 0; kk < 4; kk++)
        bq[kk] = *(const bf16x8*)(qp + (size_t)(i0 + c4) * 128 + kk * 32 + quad * 8);

    float lsum = 0.f;
    f32x4 oacc[8] = {};

#pragma unroll
    for (int t = 0; t < 4; t++) {
        int cc = w * 4 + t;
        if (cc < 16) {
            int h2 = cc >> 3, kc = cc & 7;
            int np = kc >> 2, kk = kc & 3;
            const unsigned short* kp2 = kt + (size_t)(b * 2 + h2) * 131072;
            gload_lds16(kp2 + (size_t)(np * 16 + c4) * 128 + kk * 32 + quad * 8,
                        &smem[h2 * 4096 + kc * 512]);
        } else {
            int cc2 = cc - 16, h2 = cc2 >> 3, n = cc2 & 7;
            const unsigned short* vp2 = vv + (size_t)(b * 2 + h2) * 131072;
            gload_lds16(vp2 + (size_t)(n * 16 + c4) * 1024 + quad * 8,
                        &smem[16384 + h2 * 4096 + n * 512]);
        }
    }

    for (int jt = 0; jt < 32; jt++) {
        int cur = jt & 1;
        __syncthreads();
        if (jt < 31) {
            int j0n = (jt + 1) * 32, nb = cur ^ 1;
#pragma unroll
            for (int t = 0; t < 4; t++) {
                int cc = w * 4 + t;
                if (cc < 16) {
                    int h2 = cc >> 3, kc = cc & 7;
                    int np = kc >> 2, kk = kc & 3;
                    const unsigned short* kp2 = kt + (size_t)(b * 2 + h2) * 131072;
                    gload_lds16(kp2 + (size_t)(j0n + np * 16 + c4) * 128 + kk * 32 + quad * 8,
                                &smem[nb * 8192 + h2 * 4096 + kc * 512]);
                } else {
                    int cc2 = cc - 16, h2 = cc2 >> 3, n = cc2 & 7;
                    const unsigned short* vp2 = vv + (size_t)(b * 2 + h2) * 131072;
                    gload_lds16(vp2 + (size_t)(n * 16 + c4) * 1024 + j0n + quad * 8,
                                &smem[16384 + nb * 8192 + h2 * 4096 + n * 512]);
                }
            }
        }

        f32x4 st[2] = {};
#pragma unroll
        for (int np = 0; np < 2; np++)
#pragma unroll
            for (int kk = 0; kk < 4; kk++) {
                bf16x8 ak = *(const bf16x8*)&smem[cur * 8192 + h * 4096 + (np * 4 + kk) * 512 + lane * 8];
                st[np] = __builtin_amdgcn_mfma_f32_16x16x32_bf16(ak, bq[kk], st[np], 0, 0, 0);
            }

#pragma unroll
        for (int np = 0; np < 2; np++)
#pragma unroll
            for (int r = 0; r < 4; r++) {
                float p = exp2f(st[np][r]);
                st[np][r] = p;
                lsum += p;
            }

        unsigned pk2[4];
#pragma unroll
        for (int r = 0; r < 4; r++)
            pk2[r] = packbf(st[0][r], st[1][r]);

        int sbase = ((lane & 16) ? 32 : 0) + c4;
        bool hi = (lane & 32) != 0;
        bf16x8 pa;
#pragma unroll
        for (int t = 0; t < 4; t++) {
            unsigned u  = (unsigned)__shfl((int)pk2[t], sbase);
            unsigned u2 = (unsigned)__shfl((int)pk2[t], sbase + 16);
            pa[t]     = (short)(hi ? (u >> 16)  : (u & 0xffffu));
            pa[4 + t] = (short)(hi ? (u2 >> 16) : (u2 & 0xffffu));
        }
#pragma unroll
        for (int n = 0; n < 8; n++) {
            bf16x8 bv = *(const bf16x8*)&smem[16384 + cur * 8192 + h * 4096 + n * 512 + lane * 8];
            oacc[n] = __builtin_amdgcn_mfma_f32_16x16x32_bf16(pa, bv, oacc[n], 0, 0, 0);
        }
    }

    lsum += __shfl_xor(lsum, 16);
    lsum += __shfl_xor(lsum, 32);
    float inv = 1.0f / lsum;
    float ir[4];
#pragma unroll
    for (int r = 0; r < 4; r++) ir[r] = __shfl(inv, quad * 4 + r);

    __syncthreads();   // all K/V LDS reads done -> reuse smem as O-tile
#pragma unroll
    for (int n = 0; n < 8; n++)
#pragma unroll
        for (int r = 0; r < 4; r++) {
            int il = wl * 16 + quad * 4 + r;
            int c = h * 128 + n * 16 + c4;
            smem[il * 264 + c] = f2bf(oacc[n][r] * ir[r]);
        }
    __syncthreads();

    // ---- proj + residual: wave w owns output channels [w*32, w*32+32)
    int mbase = w * 32;
    f32x4 pacc[2][4] = {};
#pragma unroll
    for (int k = 0; k < 256; k += 32) {
        bf16x8 af[2], bfr[4];
#pragma unroll
        for (int mi = 0; mi < 2; mi++)
            af[mi] = *(const bf16x8*)(wpb + (size_t)(mbase + mi * 16 + c4) * 256 + k + quad * 8);
#pragma unroll
        for (int ni = 0; ni < 4; ni++)
            bfr[ni] = *(const bf16x8*)&smem[(ni * 16 + c4) * 264 + k + quad * 8];
#pragma unroll
        for (int mi = 0; mi < 2; mi++)
#pragma unroll
            for (int ni = 0; ni < 4; ni++)
                pacc[mi][ni] = __builtin_amdgcn_mfma_f32_16x16x32_bf16(
                    af[mi], bfr[ni], pacc[mi][ni], 0, 0, 0);
    }
#pragma unroll
    for (int mi = 0; mi < 2; mi++)
#pragma unroll
        for (int ni = 0; ni < 4; ni++)
#pragma unroll
            for (int r = 0; r < 4; r++) {
                int o = mbase + mi * 16 + quad * 4 + r;
                int i = qb * 64 + ni * 16 + c4;
                size_t idx = ((size_t)b * 256 + o) * 1024 + i;
                out[idx] = pacc[mi][ni][r] + x[idx];
            }
}

// ---------------------------------------------------------------------------
extern "C" void kernel_launch(void* const* d_in, const int* in_sizes, int n_in,
                              void* d_out, int out_size, void* d_ws, size_t ws_size,
                              hipStream_t stream) {
    const float* x   = (const float*)d_in[0];
    const float* gnw = (const float*)d_in[1];
    const float* gnb = (const float*)d_in[2];
    const float* wq  = (const float*)d_in[3];
    const float* wk  = (const float*)d_in[4];
    const float* wv  = (const float*)d_in[5];
    const float* wp  = (const float*)d_in[6];
    float* out = (float*)d_out;

    char* ws = (char*)d_ws;
    float* acc = (float*)ws;                                        //   4 KiB
    unsigned short* wqb = (unsigned short*)(ws + 4096);             // 128 KiB each
    unsigned short* wkb = (unsigned short*)(ws + 4096 + 131072);
    unsigned short* wvb = (unsigned short*)(ws + 4096 + 2 * 131072);
    unsigned short* wpb = (unsigned short*)(ws + 4096 + 3 * 131072);
    size_t base = 4096 + 4 * 131072;
    const size_t SZ = (size_t)16 * 1024 * 256 * 2;  // 8 MiB each
    unsigned short* qt = (unsigned short*)(ws + base);
    unsigned short* kt = (unsigned short*)(ws + base + SZ);
    unsigned short* vv = (unsigned short*)(ws + base + 2 * SZ);

    prep<<<768, 256, 0, stream>>>(wq, wk, wv, wp, wqb, wkb, wvb, wpb, x, acc);
    qkv_fused<<<dim3(16, 4, 16), 256, 0, stream>>>(x, acc, gnw, gnb,
                                                   wqb, wkb, wvb, qt, kt, vv);
    attn_proj3<<<256, 512, 0, stream>>>(qt, kt, vv, wpb, x, out);
}